// Round 2
// baseline (202.891 us; speedup 1.0000x reference)
//
#include <hip/hip_runtime.h>
#include <hip/hip_bf16.h>
#include <stdint.h>

typedef __attribute__((ext_vector_type(8))) short bf16x8;
typedef __attribute__((ext_vector_type(4))) short bf16x4;
typedef __attribute__((ext_vector_type(4))) float f32x4;

#define T_SEQ   8192
#define D_HEAD  64
#define NHEADS  16          // B*H
#define WIN     512
#define BQ      128
#define BK      64
#define NTILES  (T_SEQ / BK)
#define LDSR    72          // padded LDS row stride in bf16 elems (144B)
#define VTR     65          // fp32 V staging row stride (odd -> conflict-free transpose reads)
#define MASKVAL (-1.0e6f)

// 16x16x16 bf16 MFMA (K=16): B-operand layout (k=quad*4+j, n=lane&15) == S^T C-layout,
// so exp'd scores feed PV directly from registers (no LDS P round-trip).
#define MFMA16(a,b,c) __builtin_amdgcn_mfma_f32_16x16x16bf16_1k(a,b,c,0,0,0)

// Single v_exp_f32. exp2f lowers to the OCML checked routine (extra range-fixup VALU);
// both are <=1 ulp on our score range, so numerics are unchanged.
extern "C" __device__ __attribute__((const)) float __ocml_native_exp2_f32(float);
__device__ __forceinline__ float fexp2(float x) { return __ocml_native_exp2_f32(x); }

__device__ __forceinline__ short f2bf(float f) {
    union { float f; uint32_t u; } v; v.f = f;
    return (short)((v.u + 0x7FFFu + ((v.u >> 16) & 1u)) >> 16);   // RNE, finite inputs
}

__device__ __forceinline__ uint32_t pkbf2(float lo, float hi) {
    union { __hip_bfloat162 h; uint32_t u; } c;
    c.h = __float22bfloat162_rn(make_float2(lo, hi));             // v_cvt_pk_bf16_f32
    return c.u;
}

// ---------------- fused, conservative 3-barrier staging (no cross-iteration LDS state) ----------------
__global__ __launch_bounds__(256, 4)
void swa_fused(const float* __restrict__ Qg, const float* __restrict__ Kg,
               const float* __restrict__ Vg, float* __restrict__ Og)
{
    __shared__ short Ks[BK * LDSR];          // [key][d]   bf16
    __shared__ short Vs[D_HEAD * LDSR];      // [d][key]   bf16 (transposed)
    __shared__ float Vtmp[BK * VTR];         // [key][d]   fp32 staging for transpose

    const int tid  = threadIdx.x;
    const int wave = tid >> 6;
    const int lane = tid & 63;
    const int lcol = lane & 15;
    const int quad = lane >> 4;

    const int g    = blockIdx.x;
    const int head = g >> 6;                            // 0..15
    const int qt   = ((g & 7) << 3) | ((g >> 3) & 7);   // 0..63 (XCD swizzle)
    const int q0   = qt * BQ;
    const int tq   = q0 >> 6;

    const size_t hoff = (size_t)head * T_SEQ * D_HEAD;
    const float* Qp = Qg + hoff;
    const float* Kp = Kg + hoff;
    const float* Vp = Vg + hoff;
    float*       Op = Og + hoff;

    const float qscale = 0.125f * 1.44269504088896340736f;  // 1/sqrt(D) * log2(e)
    const int qrow_w = q0 + wave * 32;

    // Q fragments (fp32 -> bf16 once, scale folded). Serves as B-operand of K*Q^T.
    bf16x8 qf[2][2];
    #pragma unroll
    for (int mt = 0; mt < 2; ++mt) {
        const float* qptr = Qp + (size_t)(qrow_w + mt*16 + lcol) * D_HEAD + quad * 8;
        #pragma unroll
        for (int ks = 0; ks < 2; ++ks) {
            float4 a = *(const float4*)(qptr + ks*32);
            float4 b = *(const float4*)(qptr + ks*32 + 4);
            bf16x8 f;
            f[0]=f2bf(a.x*qscale); f[1]=f2bf(a.y*qscale); f[2]=f2bf(a.z*qscale); f[3]=f2bf(a.w*qscale);
            f[4]=f2bf(b.x*qscale); f[5]=f2bf(b.y*qscale); f[6]=f2bf(b.z*qscale); f[7]=f2bf(b.w*qscale);
            qf[mt][ks] = f;
        }
    }

    // O^T accumulators: oacc[mt][nt] rows d = nt*16+quad*4+r, col q = lcol (q-group mt)
    f32x4 oacc[2][4];
    float l_run[2];
    const f32x4 zero4 = {0.f, 0.f, 0.f, 0.f};
    #pragma unroll
    for (int mt = 0; mt < 2; ++mt) {
        l_run[mt] = 0.f;
        #pragma unroll
        for (int nt = 0; nt < 4; ++nt) oacc[mt][nt] = zero4;
    }

    int t0 = (q0 - WIN) >> 6;            if (t0 < 0) t0 = 0;
    int t1 = (q0 + BQ - 1 + WIN) >> 6;   if (t1 > NTILES - 1) t1 = NTILES - 1;

    // thread-constant staging coords
    const int krow0 = tid >> 3, kc = (tid & 7) << 3;    // K: 8 floats at (row, kc)
    const int krow1 = krow0 + 32;
    const int vrow  = tid >> 4, vc = (tid & 15) << 2;   // V: float4 at (vrow+16i, vc)
    const int td    = tid >> 2, tkq = (tid & 3) << 4;   // transpose: d=td, keys tkq..tkq+15

    for (int t = t0; t <= t1; ++t) {
        // ---- issue global loads into registers (no LDS touched: safe before barrier,
        //      latency overlaps previous tile's compute tail + barrier wait) ----
        const float* ksrc = Kp + (size_t)t * BK * D_HEAD;
        const float* vsrc = Vp + (size_t)t * BK * D_HEAD;
        float4 k00 = *(const float4*)(ksrc + krow0*D_HEAD + kc);
        float4 k01 = *(const float4*)(ksrc + krow0*D_HEAD + kc + 4);
        float4 k10 = *(const float4*)(ksrc + krow1*D_HEAD + kc);
        float4 k11 = *(const float4*)(ksrc + krow1*D_HEAD + kc + 4);
        float4 v0  = *(const float4*)(vsrc + (vrow     )*D_HEAD + vc);
        float4 v1  = *(const float4*)(vsrc + (vrow + 16)*D_HEAD + vc);
        float4 v2  = *(const float4*)(vsrc + (vrow + 32)*D_HEAD + vc);
        float4 v3  = *(const float4*)(vsrc + (vrow + 48)*D_HEAD + vc);

        __syncthreads();   // S1: prev compute done -> Ks/Vs free; prev transpose done -> Vtmp free

        *(float4*)&Vtmp[(vrow     )*VTR + vc] = v0;
        *(float4*)&Vtmp[(vrow + 16)*VTR + vc] = v1;
        *(float4*)&Vtmp[(vrow + 32)*VTR + vc] = v2;
        *(float4*)&Vtmp[(vrow + 48)*VTR + vc] = v3;
        *(int4*)&Ks[krow0*LDSR + kc] = make_int4((int)pkbf2(k00.x,k00.y), (int)pkbf2(k00.z,k00.w),
                                                 (int)pkbf2(k01.x,k01.y), (int)pkbf2(k01.z,k01.w));
        *(int4*)&Ks[krow1*LDSR + kc] = make_int4((int)pkbf2(k10.x,k10.y), (int)pkbf2(k10.z,k10.w),
                                                 (int)pkbf2(k11.x,k11.y), (int)pkbf2(k11.z,k11.w));

        __syncthreads();   // S2: Vtmp (and Ks) ready

        {
            // 16 scalar LDS reads, stride VTR=65 (odd): conflict-free transpose gather
            uint32_t w0 = pkbf2(Vtmp[(tkq+ 0)*VTR + td], Vtmp[(tkq+ 1)*VTR + td]);
            uint32_t w1 = pkbf2(Vtmp[(tkq+ 2)*VTR + td], Vtmp[(tkq+ 3)*VTR + td]);
            uint32_t w2 = pkbf2(Vtmp[(tkq+ 4)*VTR + td], Vtmp[(tkq+ 5)*VTR + td]);
            uint32_t w3 = pkbf2(Vtmp[(tkq+ 6)*VTR + td], Vtmp[(tkq+ 7)*VTR + td]);
            uint32_t w4 = pkbf2(Vtmp[(tkq+ 8)*VTR + td], Vtmp[(tkq+ 9)*VTR + td]);
            uint32_t w5 = pkbf2(Vtmp[(tkq+10)*VTR + td], Vtmp[(tkq+11)*VTR + td]);
            uint32_t w6 = pkbf2(Vtmp[(tkq+12)*VTR + td], Vtmp[(tkq+13)*VTR + td]);
            uint32_t w7 = pkbf2(Vtmp[(tkq+14)*VTR + td], Vtmp[(tkq+15)*VTR + td]);
            *(int4*)&Vs[td*LDSR + tkq]     = make_int4((int)w0,(int)w1,(int)w2,(int)w3);
            *(int4*)&Vs[td*LDSR + tkq + 8] = make_int4((int)w4,(int)w5,(int)w6,(int)w7);
        }

        __syncthreads();   // S3: Vs ready

        const bool edge = (t < tq - 6) || (t > tq + 7);

        #pragma unroll
        for (int h = 0; h < 2; ++h) {            // key halves: kt = 2h, 2h+1
            // S^T tiles: sc[j][mt], C layout row=key quad*4+r, col=q lcol
            f32x4 sc[2][2];
            #pragma unroll
            for (int j = 0; j < 2; ++j) { sc[j][0] = zero4; sc[j][1] = zero4; }
            #pragma unroll
            for (int ks = 0; ks < 2; ++ks) {
                #pragma unroll
                for (int j = 0; j < 2; ++j) {
                    bf16x8 kf = *(const bf16x8*)&Ks[((2*h+j)*16 + lcol)*LDSR + ks*32 + quad*8];
                    sc[j][0] = __builtin_amdgcn_mfma_f32_16x16x32_bf16(kf, qf[0][ks], sc[j][0], 0,0,0);
                    sc[j][1] = __builtin_amdgcn_mfma_f32_16x16x32_bf16(kf, qf[1][ks], sc[j][1], 0,0,0);
                }
            }

            if (edge) {
                #pragma unroll
                for (int j = 0; j < 2; ++j) {
                    const int kg0 = t*BK + (2*h+j)*16 + quad*4;
                    #pragma unroll
                    for (int mt = 0; mt < 2; ++mt) {
                        const int qg = qrow_w + mt*16 + lcol;
                        #pragma unroll
                        for (int r = 0; r < 4; ++r) {
                            int dq = qg - (kg0 + r);
                            if (dq > WIN || dq < -WIN) sc[j][mt][r] = MASKVAL;
                        }
                    }
                }
            }

            #pragma unroll
            for (int j = 0; j < 2; ++j) {
                const int kt = 2*h + j;
                bf16x4 vf[4];
                #pragma unroll
                for (int nt = 0; nt < 4; ++nt)
                    vf[nt] = *(const bf16x4*)&Vs[(nt*16 + lcol)*LDSR + kt*16 + quad*4];
                #pragma unroll
                for (int mt = 0; mt < 2; ++mt) {
                    float p0 = fexp2(sc[j][mt][0]);
                    float p1 = fexp2(sc[j][mt][1]);
                    float p2 = fexp2(sc[j][mt][2]);
                    float p3 = fexp2(sc[j][mt][3]);
                    l_run[mt] += (p0 + p1) + (p2 + p3);
                    union { int2 i; bf16x4 v; } pf;
                    pf.i = make_int2((int)pkbf2(p0, p1), (int)pkbf2(p2, p3));
                    #pragma unroll
                    for (int nt = 0; nt < 4; ++nt)
                        oacc[mt][nt] = MFMA16(vf[nt], pf.v, oacc[mt][nt]);
                }
            }
        }
    }

    // epilogue: reduce l over quads, O^T -> O[q][d] with contiguous float4 stores
    #pragma unroll
    for (int mt = 0; mt < 2; ++mt) {
        float l = l_run[mt];
        l += __shfl_xor(l, 16, 64);
        l += __shfl_xor(l, 32, 64);
        float inv = 1.0f / l;
        const int qg = qrow_w + mt*16 + lcol;
        float* op = Op + (size_t)qg * D_HEAD + quad*4;
        #pragma unroll
        for (int nt = 0; nt < 4; ++nt) {
            float4 o = { oacc[mt][nt][0]*inv, oacc[mt][nt][1]*inv,
                         oacc[mt][nt][2]*inv, oacc[mt][nt][3]*inv };
            *(float4*)(op + nt*16) = o;
        }
    }
}

extern "C" void kernel_launch(void* const* d_in, const int* in_sizes, int n_in,
                              void* d_out, int out_size, void* d_ws, size_t ws_size,
                              hipStream_t stream)
{
    (void)in_sizes; (void)n_in; (void)out_size; (void)d_ws; (void)ws_size;
    const float* Q = (const float*)d_in[0];
    const float* K = (const float*)d_in[1];
    const float* V = (const float*)d_in[2];
    float* O = (float*)d_out;
    swa_fused<<<dim3(NHEADS * (T_SEQ / BQ)), dim3(256), 0, stream>>>(Q, K, V, O);
}

// Round 3
// 180.981 us; speedup vs baseline: 1.1211x; 1.1211x over previous
//
#include <hip/hip_runtime.h>
#include <hip/hip_bf16.h>
#include <stdint.h>

typedef __attribute__((ext_vector_type(8))) short bf16x8;
typedef __attribute__((ext_vector_type(4))) short bf16x4;
typedef __attribute__((ext_vector_type(4))) float f32x4;

#define T_SEQ   8192
#define D_HEAD  64
#define NHEADS  16          // B*H
#define WIN     512
#define BQ      128
#define BK      64
#define NTILES  (T_SEQ / BK)
#define LDSR    72          // padded LDS row stride in bf16 elems (144B)
#define MASKVAL (-1.0e6f)

#define WS_NEEDED ((size_t)2 * NHEADS * T_SEQ * D_HEAD * 2)   // Kb + Vt, bf16

// 16x16x16 bf16 MFMA (K=16): B-operand layout (k=quad*4+j, n=lane&15) == S^T C-layout,
// so exp'd scores feed PV directly from registers (no LDS P round-trip).
#define MFMA16(a,b,c) __builtin_amdgcn_mfma_f32_16x16x16bf16_1k(a,b,c,0,0,0)

// Single v_exp_f32 (verified round 2: same absmax, VALUBusy 53.5->34.2). Plain exp2f
// lowers to the OCML checked routine (~6-10 VALU instrs) and dominated VALU time.
extern "C" __device__ __attribute__((const)) float __ocml_native_exp2_f32(float);
__device__ __forceinline__ float fexp2(float x) { return __ocml_native_exp2_f32(x); }

__device__ __forceinline__ short f2bf(float f) {
    union { float f; uint32_t u; } v; v.f = f;
    return (short)((v.u + 0x7FFFu + ((v.u >> 16) & 1u)) >> 16);   // RNE, finite inputs
}

__device__ __forceinline__ uint32_t pkbf2(float lo, float hi) {
    union { __hip_bfloat162 h; uint32_t u; } c;
    c.h = __float22bfloat162_rn(make_float2(lo, hi));             // v_cvt_pk_bf16_f32
    return c.u;
}

// ---------------- prep: K -> bf16 (same layout), V -> bf16 per-64-tile transposed ----------------
// Runs at L3 speed (~9 us measured round 0) -- keeping it beats in-loop transpose (round 2: +12 us).
__global__ __launch_bounds__(256, 2)
void prep_kv(const float* __restrict__ Kg, const float* __restrict__ Vg,
             short* __restrict__ Kb, short* __restrict__ Vt)
{
    __shared__ float vt[64 * 65];
    const int tid  = threadIdx.x;
    const int tile = blockIdx.x & (NTILES - 1);
    const int head = blockIdx.x >> 7;           // NTILES = 128
    const size_t off = ((size_t)head * T_SEQ + (size_t)tile * BK) * D_HEAD;

    const float* ks = Kg + off;
    short* kd = Kb + off;
    #pragma unroll
    for (int i = 0; i < 4; ++i) {
        int idx = tid + 256 * i;
        float4 v = *(const float4*)(ks + idx * 4);
        short4 h = { f2bf(v.x), f2bf(v.y), f2bf(v.z), f2bf(v.w) };
        *(short4*)(kd + idx * 4) = h;
    }

    const float* vs = Vg + off;
    #pragma unroll
    for (int i = 0; i < 4; ++i) {
        int idx = tid + 256 * i;
        int row = idx >> 4, c4 = (idx & 15) << 2;
        float4 v = *(const float4*)(vs + row * D_HEAD + c4);
        *(float4*)&vt[row * 65 + c4] = v;
    }
    __syncthreads();
    short* vd = Vt + ((size_t)head * NTILES + tile) * (BK * D_HEAD);
    {
        int d = tid >> 2, kq = (tid & 3) << 4;
        short out[16];
        #pragma unroll
        for (int j = 0; j < 16; ++j) out[j] = f2bf(vt[(kq + j) * 65 + d]);
        *(bf16x8*)(vd + d * BK + kq)     = *(bf16x8*)&out[0];
        *(bf16x8*)(vd + d * BK + kq + 8) = *(bf16x8*)&out[8];
    }
}

// ---------------- main: S^T = K Q^T, registers feed PV directly as B-frags ----------------
__global__ __launch_bounds__(256, 4)
void swa_fwd(const float* __restrict__ Qg, const short* __restrict__ Kb,
             const short* __restrict__ Vt, float* __restrict__ Og)
{
    __shared__ short Ks[BK * LDSR];          // [key][d]
    __shared__ short Vs[D_HEAD * LDSR];      // [d][key]

    const int tid  = threadIdx.x;
    const int wave = tid >> 6;
    const int lane = tid & 63;
    const int lcol = lane & 15;
    const int quad = lane >> 4;

    const int g    = blockIdx.x;
    const int head = (g >> 3) >> 3;                     // 0..15
    const int qt   = ((g & 7) << 3) | ((g >> 3) & 7);   // 0..63 (XCD swizzle)
    const int q0   = qt * BQ;
    const int tq   = q0 >> 6;

    const float* Qp = Qg + (size_t)head * T_SEQ * D_HEAD;
    const short* Kp = Kb + (size_t)head * T_SEQ * D_HEAD;
    float*       Op = Og + (size_t)head * T_SEQ * D_HEAD;

    const float qscale = 0.125f * 1.44269504088896340736f;  // 1/sqrt(D) * log2(e)
    const int qrow_w = q0 + wave * 32;

    // Q fragments (fp32 -> bf16 once, scale folded). Serves as B-operand of K*Q^T.
    bf16x8 qf[2][2];
    #pragma unroll
    for (int mt = 0; mt < 2; ++mt) {
        const float* qptr = Qp + (size_t)(qrow_w + mt*16 + lcol) * D_HEAD + quad * 8;
        #pragma unroll
        for (int ks = 0; ks < 2; ++ks) {
            float4 a = *(const float4*)(qptr + ks*32);
            float4 b = *(const float4*)(qptr + ks*32 + 4);
            bf16x8 f;
            f[0]=f2bf(a.x*qscale); f[1]=f2bf(a.y*qscale); f[2]=f2bf(a.z*qscale); f[3]=f2bf(a.w*qscale);
            f[4]=f2bf(b.x*qscale); f[5]=f2bf(b.y*qscale); f[6]=f2bf(b.z*qscale); f[7]=f2bf(b.w*qscale);
            qf[mt][ks] = f;
        }
    }

    // O^T accumulators: oacc[mt][nt] rows d = nt*16+quad*4+r, col q = lcol (q-group mt)
    f32x4 oacc[2][4];
    float l_run[2];
    const f32x4 zero4 = {0.f, 0.f, 0.f, 0.f};
    #pragma unroll
    for (int mt = 0; mt < 2; ++mt) {
        l_run[mt] = 0.f;
        #pragma unroll
        for (int nt = 0; nt < 4; ++nt) oacc[mt][nt] = zero4;
    }

    int t0 = (q0 - WIN) >> 6;            if (t0 < 0) t0 = 0;
    int t1 = (q0 + BQ - 1 + WIN) >> 6;   if (t1 > NTILES - 1) t1 = NTILES - 1;

    // thread-constant staging coords (idx = tid and tid+256 of the bf16x8 grid)
    const int srow0 = tid >> 3, sc0 = (tid & 7) << 3;
    const int srow1 = srow0 + 32;

    for (int t = t0; t <= t1; ++t) {
        // issue staging loads into registers BEFORE the barrier (no LDS touched):
        // latency overlaps previous tile's compute tail + barrier wait (verified r2 pattern)
        const short* ksrc = Kp + (size_t)t * BK * D_HEAD;
        const short* vsrc = Vt + ((size_t)head * NTILES + t) * (BK * D_HEAD);
        bf16x8 k0 = *(const bf16x8*)(ksrc + tid * 8);
        bf16x8 k1 = *(const bf16x8*)(ksrc + (tid + 256) * 8);
        bf16x8 v0 = *(const bf16x8*)(vsrc + tid * 8);
        bf16x8 v1 = *(const bf16x8*)(vsrc + (tid + 256) * 8);

        __syncthreads();   // S1: previous compute done -> Ks/Vs free

        *(bf16x8*)&Ks[srow0 * LDSR + sc0] = k0;
        *(bf16x8*)&Ks[srow1 * LDSR + sc0] = k1;
        *(bf16x8*)&Vs[srow0 * LDSR + sc0] = v0;
        *(bf16x8*)&Vs[srow1 * LDSR + sc0] = v1;

        __syncthreads();   // S2: tile ready

        const bool edge = (t < tq - 6) || (t > tq + 7);

        #pragma unroll
        for (int h = 0; h < 2; ++h) {            // key halves: kt = 2h, 2h+1
            // S^T tiles: sc[j][mt], C layout row=key quad*4+r, col=q lcol
            f32x4 sc[2][2];
            #pragma unroll
            for (int j = 0; j < 2; ++j) { sc[j][0] = zero4; sc[j][1] = zero4; }
            #pragma unroll
            for (int ks = 0; ks < 2; ++ks) {
                #pragma unroll
                for (int j = 0; j < 2; ++j) {
                    bf16x8 kf = *(const bf16x8*)&Ks[((2*h+j)*16 + lcol)*LDSR + ks*32 + quad*8];
                    sc[j][0] = __builtin_amdgcn_mfma_f32_16x16x32_bf16(kf, qf[0][ks], sc[j][0], 0,0,0);
                    sc[j][1] = __builtin_amdgcn_mfma_f32_16x16x32_bf16(kf, qf[1][ks], sc[j][1], 0,0,0);
                }
            }

            if (edge) {
                #pragma unroll
                for (int j = 0; j < 2; ++j) {
                    const int kg0 = t*BK + (2*h+j)*16 + quad*4;
                    #pragma unroll
                    for (int mt = 0; mt < 2; ++mt) {
                        const int qg = qrow_w + mt*16 + lcol;
                        #pragma unroll
                        for (int r = 0; r < 4; ++r) {
                            int dq = qg - (kg0 + r);
                            if (dq > WIN || dq < -WIN) sc[j][mt][r] = MASKVAL;
                        }
                    }
                }
            }

            #pragma unroll
            for (int j = 0; j < 2; ++j) {
                const int kt = 2*h + j;
                bf16x4 vf[4];
                #pragma unroll
                for (int nt = 0; nt < 4; ++nt)
                    vf[nt] = *(const bf16x4*)&Vs[(nt*16 + lcol)*LDSR + kt*16 + quad*4];
                #pragma unroll
                for (int mt = 0; mt < 2; ++mt) {
                    float p0 = fexp2(sc[j][mt][0]);
                    float p1 = fexp2(sc[j][mt][1]);
                    float p2 = fexp2(sc[j][mt][2]);
                    float p3 = fexp2(sc[j][mt][3]);
                    l_run[mt] += (p0 + p1) + (p2 + p3);
                    union { int2 i; bf16x4 v; } pf;
                    pf.i = make_int2((int)pkbf2(p0, p1), (int)pkbf2(p2, p3));
                    #pragma unroll
                    for (int nt = 0; nt < 4; ++nt)
                        oacc[mt][nt] = MFMA16(vf[nt], pf.v, oacc[mt][nt]);
                }
            }
        }
    }

    // epilogue: reduce l over quads, O^T -> O[q][d] with contiguous float4 stores
    #pragma unroll
    for (int mt = 0; mt < 2; ++mt) {
        float l = l_run[mt];
        l += __shfl_xor(l, 16, 64);
        l += __shfl_xor(l, 32, 64);
        float inv = 1.0f / l;
        const int qg = qrow_w + mt*16 + lcol;
        float* op = Op + (size_t)qg * D_HEAD + quad*4;
        #pragma unroll
        for (int nt = 0; nt < 4; ++nt) {
            float4 o = { oacc[mt][nt][0]*inv, oacc[mt][nt][1]*inv,
                         oacc[mt][nt][2]*inv, oacc[mt][nt][3]*inv };
            *(float4*)(op + nt*16) = o;
        }
    }
}

// ---------------- fallback (ws too small): fused 3-barrier kernel, verified round 2 ----------------
__global__ __launch_bounds__(256, 4)
void swa_fused_fb(const float* __restrict__ Qg, const float* __restrict__ Kg,
                  const float* __restrict__ Vg, float* __restrict__ Og)
{
    __shared__ short Ks[BK * LDSR];
    __shared__ short Vs[D_HEAD * LDSR];
    __shared__ float Vtmp[BK * 65];

    const int tid  = threadIdx.x;
    const int wave = tid >> 6;
    const int lane = tid & 63;
    const int lcol = lane & 15;
    const int quad = lane >> 4;

    const int g    = blockIdx.x;
    const int head = g >> 6;
    const int qt   = ((g & 7) << 3) | ((g >> 3) & 7);
    const int q0   = qt * BQ;
    const int tq   = q0 >> 6;

    const size_t hoff = (size_t)head * T_SEQ * D_HEAD;
    const float* Qp = Qg + hoff;
    const float* Kp = Kg + hoff;
    const float* Vp = Vg + hoff;
    float*       Op = Og + hoff;

    const float qscale = 0.125f * 1.44269504088896340736f;
    const int qrow_w = q0 + wave * 32;

    bf16x8 qf[2][2];
    #pragma unroll
    for (int mt = 0; mt < 2; ++mt) {
        const float* qptr = Qp + (size_t)(qrow_w + mt*16 + lcol) * D_HEAD + quad * 8;
        #pragma unroll
        for (int ks = 0; ks < 2; ++ks) {
            float4 a = *(const float4*)(qptr + ks*32);
            float4 b = *(const float4*)(qptr + ks*32 + 4);
            bf16x8 f;
            f[0]=f2bf(a.x*qscale); f[1]=f2bf(a.y*qscale); f[2]=f2bf(a.z*qscale); f[3]=f2bf(a.w*qscale);
            f[4]=f2bf(b.x*qscale); f[5]=f2bf(b.y*qscale); f[6]=f2bf(b.z*qscale); f[7]=f2bf(b.w*qscale);
            qf[mt][ks] = f;
        }
    }

    f32x4 oacc[2][4];
    float l_run[2];
    const f32x4 zero4 = {0.f, 0.f, 0.f, 0.f};
    #pragma unroll
    for (int mt = 0; mt < 2; ++mt) {
        l_run[mt] = 0.f;
        #pragma unroll
        for (int nt = 0; nt < 4; ++nt) oacc[mt][nt] = zero4;
    }

    int t0 = (q0 - WIN) >> 6;            if (t0 < 0) t0 = 0;
    int t1 = (q0 + BQ - 1 + WIN) >> 6;   if (t1 > NTILES - 1) t1 = NTILES - 1;

    const int krow0 = tid >> 3, kc = (tid & 7) << 3;
    const int krow1 = krow0 + 32;
    const int vrow  = tid >> 4, vc = (tid & 15) << 2;
    const int td    = tid >> 2, tkq = (tid & 3) << 4;

    for (int t = t0; t <= t1; ++t) {
        const float* ksrc = Kp + (size_t)t * BK * D_HEAD;
        const float* vsrc = Vp + (size_t)t * BK * D_HEAD;
        float4 k00 = *(const float4*)(ksrc + krow0*D_HEAD + kc);
        float4 k01 = *(const float4*)(ksrc + krow0*D_HEAD + kc + 4);
        float4 k10 = *(const float4*)(ksrc + krow1*D_HEAD + kc);
        float4 k11 = *(const float4*)(ksrc + krow1*D_HEAD + kc + 4);
        float4 v0  = *(const float4*)(vsrc + (vrow     )*D_HEAD + vc);
        float4 v1  = *(const float4*)(vsrc + (vrow + 16)*D_HEAD + vc);
        float4 v2  = *(const float4*)(vsrc + (vrow + 32)*D_HEAD + vc);
        float4 v3  = *(const float4*)(vsrc + (vrow + 48)*D_HEAD + vc);

        __syncthreads();

        *(float4*)&Vtmp[(vrow     )*65 + vc] = v0;
        *(float4*)&Vtmp[(vrow + 16)*65 + vc] = v1;
        *(float4*)&Vtmp[(vrow + 32)*65 + vc] = v2;
        *(float4*)&Vtmp[(vrow + 48)*65 + vc] = v3;
        *(int4*)&Ks[krow0*LDSR + kc] = make_int4((int)pkbf2(k00.x,k00.y), (int)pkbf2(k00.z,k00.w),
                                                 (int)pkbf2(k01.x,k01.y), (int)pkbf2(k01.z,k01.w));
        *(int4*)&Ks[krow1*LDSR + kc] = make_int4((int)pkbf2(k10.x,k10.y), (int)pkbf2(k10.z,k10.w),
                                                 (int)pkbf2(k11.x,k11.y), (int)pkbf2(k11.z,k11.w));

        __syncthreads();

        {
            uint32_t w0 = pkbf2(Vtmp[(tkq+ 0)*65 + td], Vtmp[(tkq+ 1)*65 + td]);
            uint32_t w1 = pkbf2(Vtmp[(tkq+ 2)*65 + td], Vtmp[(tkq+ 3)*65 + td]);
            uint32_t w2 = pkbf2(Vtmp[(tkq+ 4)*65 + td], Vtmp[(tkq+ 5)*65 + td]);
            uint32_t w3 = pkbf2(Vtmp[(tkq+ 6)*65 + td], Vtmp[(tkq+ 7)*65 + td]);
            uint32_t w4 = pkbf2(Vtmp[(tkq+ 8)*65 + td], Vtmp[(tkq+ 9)*65 + td]);
            uint32_t w5 = pkbf2(Vtmp[(tkq+10)*65 + td], Vtmp[(tkq+11)*65 + td]);
            uint32_t w6 = pkbf2(Vtmp[(tkq+12)*65 + td], Vtmp[(tkq+13)*65 + td]);
            uint32_t w7 = pkbf2(Vtmp[(tkq+14)*65 + td], Vtmp[(tkq+15)*65 + td]);
            *(int4*)&Vs[td*LDSR + tkq]     = make_int4((int)w0,(int)w1,(int)w2,(int)w3);
            *(int4*)&Vs[td*LDSR + tkq + 8] = make_int4((int)w4,(int)w5,(int)w6,(int)w7);
        }

        __syncthreads();

        const bool edge = (t < tq - 6) || (t > tq + 7);

        #pragma unroll
        for (int h = 0; h < 2; ++h) {
            f32x4 sc[2][2];
            #pragma unroll
            for (int j = 0; j < 2; ++j) { sc[j][0] = zero4; sc[j][1] = zero4; }
            #pragma unroll
            for (int ks = 0; ks < 2; ++ks) {
                #pragma unroll
                for (int j = 0; j < 2; ++j) {
                    bf16x8 kf = *(const bf16x8*)&Ks[((2*h+j)*16 + lcol)*LDSR + ks*32 + quad*8];
                    sc[j][0] = __builtin_amdgcn_mfma_f32_16x16x32_bf16(kf, qf[0][ks], sc[j][0], 0,0,0);
                    sc[j][1] = __builtin_amdgcn_mfma_f32_16x16x32_bf16(kf, qf[1][ks], sc[j][1], 0,0,0);
                }
            }

            if (edge) {
                #pragma unroll
                for (int j = 0; j < 2; ++j) {
                    const int kg0 = t*BK + (2*h+j)*16 + quad*4;
                    #pragma unroll
                    for (int mt = 0; mt < 2; ++mt) {
                        const int qg = qrow_w + mt*16 + lcol;
                        #pragma unroll
                        for (int r = 0; r < 4; ++r) {
                            int dq = qg - (kg0 + r);
                            if (dq > WIN || dq < -WIN) sc[j][mt][r] = MASKVAL;
                        }
                    }
                }
            }

            #pragma unroll
            for (int j = 0; j < 2; ++j) {
                const int kt = 2*h + j;
                bf16x4 vf[4];
                #pragma unroll
                for (int nt = 0; nt < 4; ++nt)
                    vf[nt] = *(const bf16x4*)&Vs[(nt*16 + lcol)*LDSR + kt*16 + quad*4];
                #pragma unroll
                for (int mt = 0; mt < 2; ++mt) {
                    float p0 = fexp2(sc[j][mt][0]);
                    float p1 = fexp2(sc[j][mt][1]);
                    float p2 = fexp2(sc[j][mt][2]);
                    float p3 = fexp2(sc[j][mt][3]);
                    l_run[mt] += (p0 + p1) + (p2 + p3);
                    union { int2 i; bf16x4 v; } pf;
                    pf.i = make_int2((int)pkbf2(p0, p1), (int)pkbf2(p2, p3));
                    #pragma unroll
                    for (int nt = 0; nt < 4; ++nt)
                        oacc[mt][nt] = MFMA16(vf[nt], pf.v, oacc[mt][nt]);
                }
            }
        }
    }

    #pragma unroll
    for (int mt = 0; mt < 2; ++mt) {
        float l = l_run[mt];
        l += __shfl_xor(l, 16, 64);
        l += __shfl_xor(l, 32, 64);
        float inv = 1.0f / l;
        const int qg = qrow_w + mt*16 + lcol;
        float* op = Op + (size_t)qg * D_HEAD + quad*4;
        #pragma unroll
        for (int nt = 0; nt < 4; ++nt) {
            float4 o = { oacc[mt][nt][0]*inv, oacc[mt][nt][1]*inv,
                         oacc[mt][nt][2]*inv, oacc[mt][nt][3]*inv };
            *(float4*)(op + nt*16) = o;
        }
    }
}

extern "C" void kernel_launch(void* const* d_in, const int* in_sizes, int n_in,
                              void* d_out, int out_size, void* d_ws, size_t ws_size,
                              hipStream_t stream)
{
    const float* Q = (const float*)d_in[0];
    const float* K = (const float*)d_in[1];
    const float* V = (const float*)d_in[2];
    float* O = (float*)d_out;

    if (ws_size >= WS_NEEDED) {
        short* Kb = (short*)d_ws;
        short* Vt = Kb + (size_t)NHEADS * T_SEQ * D_HEAD;
        prep_kv<<<dim3(NHEADS * NTILES), dim3(256), 0, stream>>>(K, V, Kb, Vt);
        swa_fwd<<<dim3(NHEADS * (T_SEQ / BQ)), dim3(256), 0, stream>>>(Q, Kb, Vt, O);
    } else {
        swa_fused_fb<<<dim3(NHEADS * (T_SEQ / BQ)), dim3(256), 0, stream>>>(Q, K, V, O);
    }
}